// Round 9
// baseline (297.787 us; speedup 1.0000x reference)
//
#include <hip/hip_runtime.h>
#include <hip/hip_bf16.h>
#include <hip/hip_fp16.h>

// Problem constants (from reference)
constexpr int B = 8;
constexpr int L = 2048;
constexpr int ANG = 16;
constexpr int AMP = 48;
constexpr int H = 4;
constexpr int AQK = 12, GQK = 6;
constexpr int AV = 12, GV = 6;
constexpr int HD = 2 * GQK + AQK;      // 24
constexpr int LOOKBACK = 100;
constexpr int NTOK = B * L;            // 16384

typedef __fp16 f16x2 __attribute__((ext_vector_type(2)));

__device__ inline f16x2 pkrtz(float a, float b) {
    return __builtin_amdgcn_cvt_pkrtz(a, b);
}
__device__ inline float2 up2(f16x2 v) { return make_float2((float)v[0], (float)v[1]); }

union F4H { float4 v; f16x2 h[4]; };

// ---------------- Fused kernel: QKV projection + banded attention (v4, fp16 tiles) ----------------
// Block = (b, h, 64-query tile), 256 threads = 4 waves.
// Phase A: stage x rows [kmin, q0+63] into LDS as fp16 (rows of 41 f16x2; 41 odd
//          -> conflict-free per-row column reads). 26.7 KB.
// Phase B: threads 0..nrows-1 -> k,v row; threads 192..255 -> q rows. proj_row()
//          reads the fp16 x row, fp32 weights (wave-uniform addresses -> s_load),
//          accumulates fp32.
// Phase B2: K/V rows packed to fp16 (3 float4 = 24 halves per row, 48B stride;
//          quad-bank = (3r+slot)%8, 3 coprime 8 -> natural spread). Q fp32 tile.
//          Tiles UNION the stage (26.7 KB total -> 4+ blocks/CU = grid cap).
// Phase C: wave = 16 queries x 4 split-K groups; two-pass softmax (scores in
//          regs); fp32 accumulation; shfl_xor merge. att fp32 token-major.
constexpr int TQ     = 64;
constexpr int GROUPS = 4;
constexpr int CHUNK  = 25;                 // ceil(LOOKBACK/GROUPS)
constexpr int MAXK   = TQ + LOOKBACK - 1;  // 163
constexpr int NT     = L / TQ;             // 32

struct StageT { f16x2 xall[MAXK][41]; };   // cols 0..23 amp(48h), 24..31 ang_re(16h), 32..39 ang_im(16h), 40 pad
struct TileT  {
    float4 Ks[MAXK][3];                    // fp16-packed rows, 48B stride
    float4 Vs[MAXK][3];
    float4 Qs[TQ][7];                      // fp32, 112B stride
};
union SharedU { StageT s; TileT t; };      // 26732 B

// out[24] order: [re0..5, im0..5, amp0..11] (matches q/k/v d-order)
__device__ inline void proj_row(const f16x2* __restrict__ xrow, int h,
                                const float* __restrict__ Wamp,
                                const float* __restrict__ Wang_r,
                                const float* __restrict__ Wang_i,
                                float out[24])
{
    float a[12];
    #pragma unroll
    for (int c = 0; c < 12; ++c) a[c] = 0.f;
    #pragma unroll
    for (int i2 = 0; i2 < 24; ++i2) {
        float2 x2 = up2(xrow[i2]);
        const float* w0 = Wamp + (2 * i2) * 48 + h * AQK;
        const float* w1 = Wamp + (2 * i2 + 1) * 48 + h * AQK;
        #pragma unroll
        for (int c = 0; c < 12; ++c)
            a[c] += x2.x * w0[c] + x2.y * w1[c];
    }
    float rr[6], im[6];
    #pragma unroll
    for (int c = 0; c < 6; ++c) { rr[c] = 0.f; im[c] = 0.f; }
    #pragma unroll
    for (int i2 = 0; i2 < 8; ++i2) {
        float2 xr2 = up2(xrow[24 + i2]);
        float2 xi2 = up2(xrow[32 + i2]);
        const float* wr0 = Wang_r + (2 * i2) * 24 + h * GQK;
        const float* wi0 = Wang_i + (2 * i2) * 24 + h * GQK;
        const float* wr1 = Wang_r + (2 * i2 + 1) * 24 + h * GQK;
        const float* wi1 = Wang_i + (2 * i2 + 1) * 24 + h * GQK;
        #pragma unroll
        for (int c = 0; c < 6; ++c) {
            rr[c] += xr2.x * wr0[c] - xi2.x * wi0[c] + xr2.y * wr1[c] - xi2.y * wi1[c];
            im[c] += xr2.x * wi0[c] + xi2.x * wr0[c] + xr2.y * wi1[c] + xi2.y * wr1[c];
        }
    }
    #pragma unroll
    for (int c = 0; c < 6; ++c) { out[c] = rr[c]; out[6 + c] = im[c]; }
    #pragma unroll
    for (int c = 0; c < 12; ++c) out[12 + c] = a[c];
}

__global__ __launch_bounds__(256, 4) void fused_qkv_attn4_kernel(
    const float* __restrict__ x_ang, const float* __restrict__ x_amp,
    const float* __restrict__ Wq_amp, const float* __restrict__ Wk_amp,
    const float* __restrict__ Wv_amp,
    const float* __restrict__ Wq_ang_r, const float* __restrict__ Wq_ang_i,
    const float* __restrict__ Wk_ang_r, const float* __restrict__ Wk_ang_i,
    const float* __restrict__ Wv_ang_r, const float* __restrict__ Wv_ang_i,
    float* __restrict__ att)
{
    __shared__ SharedU u;

    const int tid = threadIdx.x;
    const int bh  = blockIdx.x / NT;
    const int qt  = blockIdx.x % NT;
    const int b   = bh / H, h = bh % H;
    const int q0  = qt * TQ;
    int kmin = q0 - (LOOKBACK - 1); if (kmin < 0) kmin = 0;
    const int nrows = q0 + TQ - kmin;      // <= 163
    const int qoff  = q0 - kmin;

    // ---------------- Phase A: stage x as fp16 ----------------
    {
        const float4* xm4 = (const float4*)(x_amp + ((size_t)b * L + kmin) * AMP);
        const float4* xg4 = (const float4*)(x_ang + ((size_t)b * L + kmin) * (2 * ANG));
        int namp = nrows * 12;
        int ntot = namp + nrows * 8;
        for (int c = tid; c < ntot; c += 256) {
            if (c < namp) {
                int r = c / 12, i = c % 12;
                float4 t4 = xm4[c];
                u.s.xall[r][2 * i]     = pkrtz(t4.x, t4.y);
                u.s.xall[r][2 * i + 1] = pkrtz(t4.z, t4.w);
            } else {
                int c2 = c - namp;
                int r = c2 / 8, i = c2 % 8;
                float4 t4 = xg4[c2];
                u.s.xall[r][24 + 2 * i]     = pkrtz(t4.x, t4.y);
                u.s.xall[r][24 + 2 * i + 1] = pkrtz(t4.z, t4.w);
            }
        }
    }
    __syncthreads();

    // ---------------- Phase B: projections (fp32 accum) ----------------
    const bool kvact = (tid < nrows);
    const bool qact  = (tid >= 192);
    const int  qrow  = tid - 192;

    float kd[24], vd[24], qd[24];
    if (kvact) {
        const f16x2* xrow = u.s.xall[tid];
        proj_row(xrow, h, Wk_amp, Wk_ang_r, Wk_ang_i, kd);
        proj_row(xrow, h, Wv_amp, Wv_ang_r, Wv_ang_i, vd);
    }
    if (qact) {
        const f16x2* xrow = u.s.xall[qoff + qrow];
        proj_row(xrow, h, Wq_amp, Wq_ang_r, Wq_ang_i, qd);
    }
    __syncthreads();   // stage reads complete (union about to be overwritten)

    // ---------------- Phase B2: write tiles ----------------
    if (kvact) {
        int r = tid;
        #pragma unroll
        for (int sl = 0; sl < 3; ++sl) {
            F4H pk_, pv_;
            #pragma unroll
            for (int j = 0; j < 4; ++j) {
                pk_.h[j] = pkrtz(kd[8 * sl + 2 * j], kd[8 * sl + 2 * j + 1]);
                pv_.h[j] = pkrtz(vd[8 * sl + 2 * j], vd[8 * sl + 2 * j + 1]);
            }
            u.t.Ks[r][sl] = pk_.v;
            u.t.Vs[r][sl] = pv_.v;
        }
    } else if (tid < MAXK) {               // zero-fill rows [nrows, MAXK)
        float4 z = make_float4(0.f, 0.f, 0.f, 0.f);
        #pragma unroll
        for (int sl = 0; sl < 3; ++sl) { u.t.Ks[tid][sl] = z; u.t.Vs[tid][sl] = z; }
    }
    if (qact) {
        #pragma unroll
        for (int s = 0; s < 6; ++s)
            u.t.Qs[qrow][s] = make_float4(qd[4*s], qd[4*s+1], qd[4*s+2], qd[4*s+3]);
    }
    __syncthreads();

    // ---------------- Phase C: two-pass split-K softmax (groups within wave) ----------------
    const int lane = tid & 63;
    const int w    = tid >> 6;             // wave id -> queries w*16..w*16+15
    const int q16  = lane & 15;
    const int g    = lane >> 4;            // split-K group 0..3
    const int ql   = w * 16 + q16;
    const int qi   = q0 + ql;

    float qf[24];
    #pragma unroll
    for (int s = 0; s < 6; ++s) {
        float4 t4 = u.t.Qs[ql][s];
        qf[4*s] = t4.x; qf[4*s+1] = t4.y; qf[4*s+2] = t4.z; qf[4*s+3] = t4.w;
    }

    const float scale = 0.2041241452319315f; // 1/sqrt(24)
    int j0 = qi - (LOOKBACK - 1); if (j0 < 0) j0 = 0;
    const int jstart = j0 + g;

    float sc[CHUNK];
    #pragma unroll
    for (int t = 0; t < CHUNK; ++t) {
        int j = jstart + t * GROUPS;
        int r = j - kmin;
        F4H k0, k1, k2;
        k0.v = u.t.Ks[r][0]; k1.v = u.t.Ks[r][1]; k2.v = u.t.Ks[r][2];
        float d = 0.f;
        #pragma unroll
        for (int jj = 0; jj < 4; ++jj) {
            float2 a0 = up2(k0.h[jj]); d += a0.x * qf[2*jj]      + a0.y * qf[2*jj+1];
            float2 a1 = up2(k1.h[jj]); d += a1.x * qf[8 + 2*jj]  + a1.y * qf[8 + 2*jj+1];
            float2 a2 = up2(k2.h[jj]); d += a2.x * qf[16 + 2*jj] + a2.y * qf[16 + 2*jj+1];
        }
        sc[t] = (j <= qi) ? d * scale : -3.0e38f;
    }
    float m = sc[0];
    #pragma unroll
    for (int t = 1; t < CHUNK; ++t) m = fmaxf(m, sc[t]);
    float ssum = 0.f;
    #pragma unroll
    for (int t = 0; t < CHUNK; ++t) {
        float p = __expf(sc[t] - m);
        p = (sc[t] > -1.0e37f) ? p : 0.f;
        sc[t] = p;
        ssum += p;
    }
    float o[24];
    #pragma unroll
    for (int e = 0; e < 24; ++e) o[e] = 0.f;
    #pragma unroll
    for (int t = 0; t < CHUNK; ++t) {
        float p = sc[t];
        int j = jstart + t * GROUPS;
        int r = j - kmin;
        F4H v0, v1, v2;
        v0.v = u.t.Vs[r][0]; v1.v = u.t.Vs[r][1]; v2.v = u.t.Vs[r][2];
        #pragma unroll
        for (int jj = 0; jj < 4; ++jj) {
            float2 a0 = up2(v0.h[jj]); o[2*jj]      += p * a0.x; o[2*jj+1]      += p * a0.y;
            float2 a1 = up2(v1.h[jj]); o[8 + 2*jj]  += p * a1.x; o[8 + 2*jj+1]  += p * a1.y;
            float2 a2 = up2(v2.h[jj]); o[16 + 2*jj] += p * a2.x; o[16 + 2*jj+1] += p * a2.y;
        }
    }

    // merge across the 4 groups (lanes xor 16, xor 32) — exact algebra
    #pragma unroll
    for (int d = 16; d <= 32; d <<= 1) {
        float m2 = __shfl_xor(m, d);
        float s2 = __shfl_xor(ssum, d);
        float mm = fmaxf(m, m2);
        float c1 = __expf(m - mm);
        float c2 = __expf(m2 - mm);
        ssum = ssum * c1 + s2 * c2;
        #pragma unroll
        for (int e = 0; e < 24; ++e)
            o[e] = o[e] * c1 + __shfl_xor(o[e], d) * c2;
        m = mm;
    }
    float inv = 1.f / ssum;

    // write att token-major [tok][h*24+d]; 4 duplicate lanes split the 6 slots
    {
        float4* dst = (float4*)att + (size_t)(b * L + qi) * 24 + h * 6;
        if (g == 0) {
            dst[0] = make_float4(o[0]*inv,  o[1]*inv,  o[2]*inv,  o[3]*inv);
            dst[4] = make_float4(o[16]*inv, o[17]*inv, o[18]*inv, o[19]*inv);
        } else if (g == 1) {
            dst[1] = make_float4(o[4]*inv,  o[5]*inv,  o[6]*inv,  o[7]*inv);
            dst[5] = make_float4(o[20]*inv, o[21]*inv, o[22]*inv, o[23]*inv);
        } else if (g == 2) {
            dst[2] = make_float4(o[8]*inv,  o[9]*inv,  o[10]*inv, o[11]*inv);
        } else {
            dst[3] = make_float4(o[12]*inv, o[13]*inv, o[14]*inv, o[15]*inv);
        }
    }
}

// ---------------- Kernel 2: output projections (4 outputs per thread) ----------------
constexpr int PJ_AMP_BLOCKS = (NTOK * 12) / 256;   // 768
constexpr int PJ_ANG_BLOCKS = (NTOK * 4) / 256;    // 256

__global__ __launch_bounds__(256) void proj4_kernel(
    const float* __restrict__ att,
    const float* __restrict__ Wout_amp, const float* __restrict__ bout_amp,
    const float* __restrict__ Wout_ang_r, const float* __restrict__ Wout_ang_i,
    float* __restrict__ out)
{
    constexpr size_t ANG_OUT = (size_t)NTOK * ANG; // 262144
    int bid = blockIdx.x;

    if (bid < PJ_AMP_BLOCKS) {
        int gidx = bid * 256 + threadIdx.x;
        int c4   = (gidx % 12) * 4;     // 0..44
        int tok  = gidx / 12;
        const float4* at4 = (const float4*)att + (size_t)tok * 24;

        float a[48];
        #pragma unroll
        for (int h = 0; h < H; ++h) {
            #pragma unroll
            for (int i = 0; i < 3; ++i) {
                float4 t = at4[h * 6 + 3 + i];
                a[h*12 + 4*i+0]=t.x; a[h*12 + 4*i+1]=t.y;
                a[h*12 + 4*i+2]=t.z; a[h*12 + 4*i+3]=t.w;
            }
        }
        float4 acc = *(const float4*)(bout_amp + c4);
        #pragma unroll
        for (int i = 0; i < 48; ++i) {
            float4 w = *(const float4*)(Wout_amp + i * 48 + c4);
            acc.x += a[i]*w.x; acc.y += a[i]*w.y; acc.z += a[i]*w.z; acc.w += a[i]*w.w;
        }
        *(float4*)(out + 2*ANG_OUT + (size_t)tok * 48 + c4) = acc;
    } else {
        int gidx = (bid - PJ_AMP_BLOCKS) * 256 + threadIdx.x;
        int c4   = (gidx % 4) * 4;      // 0,4,8,12
        int tok  = gidx / 4;
        const float4* at4 = (const float4*)att + (size_t)tok * 24;

        float ar[24], ai[24];
        #pragma unroll
        for (int h = 0; h < H; ++h) {
            float4 t0 = at4[h*6+0], t1 = at4[h*6+1], t2 = at4[h*6+2];
            ar[h*6+0]=t0.x; ar[h*6+1]=t0.y; ar[h*6+2]=t0.z; ar[h*6+3]=t0.w;
            ar[h*6+4]=t1.x; ar[h*6+5]=t1.y;
            ai[h*6+0]=t1.z; ai[h*6+1]=t1.w;
            ai[h*6+2]=t2.x; ai[h*6+3]=t2.y; ai[h*6+4]=t2.z; ai[h*6+5]=t2.w;
        }
        float4 accr = make_float4(0.f,0.f,0.f,0.f);
        float4 acci = make_float4(0.f,0.f,0.f,0.f);
        #pragma unroll
        for (int i = 0; i < 24; ++i) {
            float4 wr = *(const float4*)(Wout_ang_r + i * 16 + c4);
            float4 wi = *(const float4*)(Wout_ang_i + i * 16 + c4);
            float r = ar[i], im = ai[i];
            accr.x += r*wr.x - im*wi.x;  accr.y += r*wr.y - im*wi.y;
            accr.z += r*wr.z - im*wi.z;  accr.w += r*wr.w - im*wi.w;
            acci.x += r*wi.x + im*wr.x;  acci.y += r*wi.y + im*wr.y;
            acci.z += r*wi.z + im*wr.z;  acci.w += r*wi.w + im*wr.w;
        }
        *(float4*)(out + (size_t)tok * 16 + c4)           = accr;
        *(float4*)(out + ANG_OUT + (size_t)tok * 16 + c4) = acci;
    }
}

// -------------------- Launch --------------------
extern "C" void kernel_launch(void* const* d_in, const int* in_sizes, int n_in,
                              void* d_out, int out_size, void* d_ws, size_t ws_size,
                              hipStream_t stream)
{
    const float* x_ang      = (const float*)d_in[0];
    const float* x_amp      = (const float*)d_in[1];
    const float* Wq_amp     = (const float*)d_in[2];
    const float* Wk_amp     = (const float*)d_in[3];
    const float* Wv_amp     = (const float*)d_in[4];
    const float* Wq_ang_r   = (const float*)d_in[5];
    const float* Wq_ang_i   = (const float*)d_in[6];
    const float* Wk_ang_r   = (const float*)d_in[7];
    const float* Wk_ang_i   = (const float*)d_in[8];
    const float* Wv_ang_r   = (const float*)d_in[9];
    const float* Wv_ang_i   = (const float*)d_in[10];
    const float* Wout_amp   = (const float*)d_in[11];
    const float* bout_amp   = (const float*)d_in[12];
    const float* Wout_ang_r = (const float*)d_in[13];
    const float* Wout_ang_i = (const float*)d_in[14];

    float* out = (float*)d_out;
    float* att = (float*)d_ws;   // NTOK * 96 floats = 6.29 MB, token-major

    fused_qkv_attn4_kernel<<<B * H * NT, 256, 0, stream>>>(
        x_ang, x_amp, Wq_amp, Wk_amp, Wv_amp,
        Wq_ang_r, Wq_ang_i, Wk_ang_r, Wk_ang_i, Wv_ang_r, Wv_ang_i,
        att);

    proj4_kernel<<<PJ_AMP_BLOCKS + PJ_ANG_BLOCKS, 256, 0, stream>>>(
        att, Wout_amp, bout_amp, Wout_ang_r, Wout_ang_i, out);
}

// Round 10
// 152.626 us; speedup vs baseline: 1.9511x; 1.9511x over previous
//
#include <hip/hip_runtime.h>
#include <hip/hip_bf16.h>
#include <hip/hip_fp16.h>

// Problem constants (from reference)
constexpr int B = 8;
constexpr int L = 2048;
constexpr int ANG = 16;
constexpr int AMP = 48;
constexpr int H = 4;
constexpr int AQK = 12, GQK = 6;
constexpr int AV = 12, GV = 6;
constexpr int HD = 2 * GQK + AQK;      // 24
constexpr int LOOKBACK = 100;
constexpr int NTOK = B * L;            // 16384

typedef __fp16 f16x2 __attribute__((ext_vector_type(2)));

__device__ inline f16x2 pkrtz(float a, float b) {
    return __builtin_amdgcn_cvt_pkrtz(a, b);
}
__device__ inline float2 up2(f16x2 v) { return make_float2((float)v[0], (float)v[1]); }

union F4H { float4 v; f16x2 h[4]; };

// ---------------- Fused kernel: QKV projection + banded attention (v4, fp16 tiles) ----------------
// Block = (b, h, 64-query tile), 256 threads = 4 waves.
// Phase A: stage x rows [kmin, q0+63] into LDS as fp16 (rows of 41 f16x2).
// Phase B: threads 0..nrows-1 -> k,v row; threads 192..255 -> q rows; fp32 accum.
// Phase B2: K/V fp16-packed rows (48B stride; quad-bank (3r+slot)%8 spread),
//           Q fp32 [64][7]; tiles UNION the stage. 26.7 KB LDS.
// Phase C: wave = 16 queries x 4 split-K groups; two-pass softmax; shfl merge.
// NOTE: __launch_bounds__(256, 2) — R9's (256,4) capped VGPR at 64 and spilled
// ~450 MB/dispatch to scratch (measured). 2 waves/EU -> cap 256, no spill.
constexpr int TQ     = 64;
constexpr int GROUPS = 4;
constexpr int CHUNK  = 25;                 // ceil(LOOKBACK/GROUPS)
constexpr int MAXK   = TQ + LOOKBACK - 1;  // 163
constexpr int NT     = L / TQ;             // 32

struct StageT { f16x2 xall[MAXK][41]; };   // cols 0..23 amp(48h), 24..31 ang_re, 32..39 ang_im, 40 pad
struct TileT  {
    float4 Ks[MAXK][3];                    // fp16-packed rows, 48B stride
    float4 Vs[MAXK][3];
    float4 Qs[TQ][7];                      // fp32, 112B stride
};
union SharedU { StageT s; TileT t; };      // 26732 B

// out[24] order: [re0..5, im0..5, amp0..11] (matches q/k/v d-order)
__device__ inline void proj_row(const f16x2* __restrict__ xrow, int h,
                                const float* __restrict__ Wamp,
                                const float* __restrict__ Wang_r,
                                const float* __restrict__ Wang_i,
                                float out[24])
{
    float a[12];
    #pragma unroll
    for (int c = 0; c < 12; ++c) a[c] = 0.f;
    #pragma unroll
    for (int i2 = 0; i2 < 24; ++i2) {
        float2 x2 = up2(xrow[i2]);
        const float* w0 = Wamp + (2 * i2) * 48 + h * AQK;
        const float* w1 = Wamp + (2 * i2 + 1) * 48 + h * AQK;
        #pragma unroll
        for (int c = 0; c < 12; ++c)
            a[c] += x2.x * w0[c] + x2.y * w1[c];
    }
    float rr[6], im[6];
    #pragma unroll
    for (int c = 0; c < 6; ++c) { rr[c] = 0.f; im[c] = 0.f; }
    #pragma unroll
    for (int i2 = 0; i2 < 8; ++i2) {
        float2 xr2 = up2(xrow[24 + i2]);
        float2 xi2 = up2(xrow[32 + i2]);
        const float* wr0 = Wang_r + (2 * i2) * 24 + h * GQK;
        const float* wi0 = Wang_i + (2 * i2) * 24 + h * GQK;
        const float* wr1 = Wang_r + (2 * i2 + 1) * 24 + h * GQK;
        const float* wi1 = Wang_i + (2 * i2 + 1) * 24 + h * GQK;
        #pragma unroll
        for (int c = 0; c < 6; ++c) {
            rr[c] += xr2.x * wr0[c] - xi2.x * wi0[c] + xr2.y * wr1[c] - xi2.y * wi1[c];
            im[c] += xr2.x * wi0[c] + xi2.x * wr0[c] + xr2.y * wi1[c] + xi2.y * wr1[c];
        }
    }
    #pragma unroll
    for (int c = 0; c < 6; ++c) { out[c] = rr[c]; out[6 + c] = im[c]; }
    #pragma unroll
    for (int c = 0; c < 12; ++c) out[12 + c] = a[c];
}

__global__ __launch_bounds__(256, 2) void fused_qkv_attn5_kernel(
    const float* __restrict__ x_ang, const float* __restrict__ x_amp,
    const float* __restrict__ Wq_amp, const float* __restrict__ Wk_amp,
    const float* __restrict__ Wv_amp,
    const float* __restrict__ Wq_ang_r, const float* __restrict__ Wq_ang_i,
    const float* __restrict__ Wk_ang_r, const float* __restrict__ Wk_ang_i,
    const float* __restrict__ Wv_ang_r, const float* __restrict__ Wv_ang_i,
    float* __restrict__ att)
{
    __shared__ SharedU u;

    const int tid = threadIdx.x;
    const int bh  = blockIdx.x / NT;
    const int qt  = blockIdx.x % NT;
    const int b   = bh / H, h = bh % H;
    const int q0  = qt * TQ;
    int kmin = q0 - (LOOKBACK - 1); if (kmin < 0) kmin = 0;
    const int nrows = q0 + TQ - kmin;      // <= 163
    const int qoff  = q0 - kmin;

    // ---------------- Phase A: stage x as fp16 ----------------
    {
        const float4* xm4 = (const float4*)(x_amp + ((size_t)b * L + kmin) * AMP);
        const float4* xg4 = (const float4*)(x_ang + ((size_t)b * L + kmin) * (2 * ANG));
        int namp = nrows * 12;
        int ntot = namp + nrows * 8;
        for (int c = tid; c < ntot; c += 256) {
            if (c < namp) {
                int r = c / 12, i = c % 12;
                float4 t4 = xm4[c];
                u.s.xall[r][2 * i]     = pkrtz(t4.x, t4.y);
                u.s.xall[r][2 * i + 1] = pkrtz(t4.z, t4.w);
            } else {
                int c2 = c - namp;
                int r = c2 / 8, i = c2 % 8;
                float4 t4 = xg4[c2];
                u.s.xall[r][24 + 2 * i]     = pkrtz(t4.x, t4.y);
                u.s.xall[r][24 + 2 * i + 1] = pkrtz(t4.z, t4.w);
            }
        }
    }
    __syncthreads();

    // ---------------- Phase B: projections (fp32 accum) ----------------
    const bool kvact = (tid < nrows);
    const bool qact  = (tid >= 192);
    const int  qrow  = tid - 192;

    float kd[24], vd[24], qd[24];
    if (kvact) {
        const f16x2* xrow = u.s.xall[tid];
        proj_row(xrow, h, Wk_amp, Wk_ang_r, Wk_ang_i, kd);
        proj_row(xrow, h, Wv_amp, Wv_ang_r, Wv_ang_i, vd);
    }
    if (qact) {
        const f16x2* xrow = u.s.xall[qoff + qrow];
        proj_row(xrow, h, Wq_amp, Wq_ang_r, Wq_ang_i, qd);
    }
    __syncthreads();   // stage reads complete (union about to be overwritten)

    // ---------------- Phase B2: write tiles ----------------
    if (kvact) {
        int r = tid;
        #pragma unroll
        for (int sl = 0; sl < 3; ++sl) {
            F4H pk_, pv_;
            #pragma unroll
            for (int j = 0; j < 4; ++j) {
                pk_.h[j] = pkrtz(kd[8 * sl + 2 * j], kd[8 * sl + 2 * j + 1]);
                pv_.h[j] = pkrtz(vd[8 * sl + 2 * j], vd[8 * sl + 2 * j + 1]);
            }
            u.t.Ks[r][sl] = pk_.v;
            u.t.Vs[r][sl] = pv_.v;
        }
    } else if (tid < MAXK) {               // zero-fill rows [nrows, MAXK)
        float4 z = make_float4(0.f, 0.f, 0.f, 0.f);
        #pragma unroll
        for (int sl = 0; sl < 3; ++sl) { u.t.Ks[tid][sl] = z; u.t.Vs[tid][sl] = z; }
    }
    if (qact) {
        #pragma unroll
        for (int s = 0; s < 6; ++s)
            u.t.Qs[qrow][s] = make_float4(qd[4*s], qd[4*s+1], qd[4*s+2], qd[4*s+3]);
    }
    __syncthreads();

    // ---------------- Phase C: two-pass split-K softmax (groups within wave) ----------------
    const int lane = tid & 63;
    const int w    = tid >> 6;             // wave id -> queries w*16..w*16+15
    const int q16  = lane & 15;
    const int g    = lane >> 4;            // split-K group 0..3
    const int ql   = w * 16 + q16;
    const int qi   = q0 + ql;

    float qf[24];
    #pragma unroll
    for (int s = 0; s < 6; ++s) {
        float4 t4 = u.t.Qs[ql][s];
        qf[4*s] = t4.x; qf[4*s+1] = t4.y; qf[4*s+2] = t4.z; qf[4*s+3] = t4.w;
    }

    const float scale = 0.2041241452319315f; // 1/sqrt(24)
    int j0 = qi - (LOOKBACK - 1); if (j0 < 0) j0 = 0;
    const int jstart = j0 + g;

    float sc[CHUNK];
    #pragma unroll
    for (int t = 0; t < CHUNK; ++t) {
        int j = jstart + t * GROUPS;
        int r = j - kmin;
        F4H k0, k1, k2;
        k0.v = u.t.Ks[r][0]; k1.v = u.t.Ks[r][1]; k2.v = u.t.Ks[r][2];
        float d = 0.f;
        #pragma unroll
        for (int jj = 0; jj < 4; ++jj) {
            float2 a0 = up2(k0.h[jj]); d += a0.x * qf[2*jj]      + a0.y * qf[2*jj+1];
            float2 a1 = up2(k1.h[jj]); d += a1.x * qf[8 + 2*jj]  + a1.y * qf[8 + 2*jj+1];
            float2 a2 = up2(k2.h[jj]); d += a2.x * qf[16 + 2*jj] + a2.y * qf[16 + 2*jj+1];
        }
        sc[t] = (j <= qi) ? d * scale : -3.0e38f;
    }
    float m = sc[0];
    #pragma unroll
    for (int t = 1; t < CHUNK; ++t) m = fmaxf(m, sc[t]);
    float ssum = 0.f;
    #pragma unroll
    for (int t = 0; t < CHUNK; ++t) {
        float p = __expf(sc[t] - m);
        p = (sc[t] > -1.0e37f) ? p : 0.f;
        sc[t] = p;
        ssum += p;
    }
    float o[24];
    #pragma unroll
    for (int e = 0; e < 24; ++e) o[e] = 0.f;
    #pragma unroll
    for (int t = 0; t < CHUNK; ++t) {
        float p = sc[t];
        int j = jstart + t * GROUPS;
        int r = j - kmin;
        F4H v0, v1, v2;
        v0.v = u.t.Vs[r][0]; v1.v = u.t.Vs[r][1]; v2.v = u.t.Vs[r][2];
        #pragma unroll
        for (int jj = 0; jj < 4; ++jj) {
            float2 a0 = up2(v0.h[jj]); o[2*jj]      += p * a0.x; o[2*jj+1]      += p * a0.y;
            float2 a1 = up2(v1.h[jj]); o[8 + 2*jj]  += p * a1.x; o[8 + 2*jj+1]  += p * a1.y;
            float2 a2 = up2(v2.h[jj]); o[16 + 2*jj] += p * a2.x; o[16 + 2*jj+1] += p * a2.y;
        }
    }

    // merge across the 4 groups (lanes xor 16, xor 32) — exact algebra
    #pragma unroll
    for (int d = 16; d <= 32; d <<= 1) {
        float m2 = __shfl_xor(m, d);
        float s2 = __shfl_xor(ssum, d);
        float mm = fmaxf(m, m2);
        float c1 = __expf(m - mm);
        float c2 = __expf(m2 - mm);
        ssum = ssum * c1 + s2 * c2;
        #pragma unroll
        for (int e = 0; e < 24; ++e)
            o[e] = o[e] * c1 + __shfl_xor(o[e], d) * c2;
        m = mm;
    }
    float inv = 1.f / ssum;

    // write att token-major [tok][h*24+d]; 4 duplicate lanes split the 6 slots
    {
        float4* dst = (float4*)att + (size_t)(b * L + qi) * 24 + h * 6;
        if (g == 0) {
            dst[0] = make_float4(o[0]*inv,  o[1]*inv,  o[2]*inv,  o[3]*inv);
            dst[4] = make_float4(o[16]*inv, o[17]*inv, o[18]*inv, o[19]*inv);
        } else if (g == 1) {
            dst[1] = make_float4(o[4]*inv,  o[5]*inv,  o[6]*inv,  o[7]*inv);
            dst[5] = make_float4(o[20]*inv, o[21]*inv, o[22]*inv, o[23]*inv);
        } else if (g == 2) {
            dst[2] = make_float4(o[8]*inv,  o[9]*inv,  o[10]*inv, o[11]*inv);
        } else {
            dst[3] = make_float4(o[12]*inv, o[13]*inv, o[14]*inv, o[15]*inv);
        }
    }
}

// ---------------- Kernel 2: output projections (4 outputs per thread) ----------------
constexpr int PJ_AMP_BLOCKS = (NTOK * 12) / 256;   // 768
constexpr int PJ_ANG_BLOCKS = (NTOK * 4) / 256;    // 256

__global__ __launch_bounds__(256) void proj4_kernel(
    const float* __restrict__ att,
    const float* __restrict__ Wout_amp, const float* __restrict__ bout_amp,
    const float* __restrict__ Wout_ang_r, const float* __restrict__ Wout_ang_i,
    float* __restrict__ out)
{
    constexpr size_t ANG_OUT = (size_t)NTOK * ANG; // 262144
    int bid = blockIdx.x;

    if (bid < PJ_AMP_BLOCKS) {
        int gidx = bid * 256 + threadIdx.x;
        int c4   = (gidx % 12) * 4;     // 0..44
        int tok  = gidx / 12;
        const float4* at4 = (const float4*)att + (size_t)tok * 24;

        float a[48];
        #pragma unroll
        for (int h = 0; h < H; ++h) {
            #pragma unroll
            for (int i = 0; i < 3; ++i) {
                float4 t = at4[h * 6 + 3 + i];
                a[h*12 + 4*i+0]=t.x; a[h*12 + 4*i+1]=t.y;
                a[h*12 + 4*i+2]=t.z; a[h*12 + 4*i+3]=t.w;
            }
        }
        float4 acc = *(const float4*)(bout_amp + c4);
        #pragma unroll
        for (int i = 0; i < 48; ++i) {
            float4 w = *(const float4*)(Wout_amp + i * 48 + c4);
            acc.x += a[i]*w.x; acc.y += a[i]*w.y; acc.z += a[i]*w.z; acc.w += a[i]*w.w;
        }
        *(float4*)(out + 2*ANG_OUT + (size_t)tok * 48 + c4) = acc;
    } else {
        int gidx = (bid - PJ_AMP_BLOCKS) * 256 + threadIdx.x;
        int c4   = (gidx % 4) * 4;      // 0,4,8,12
        int tok  = gidx / 4;
        const float4* at4 = (const float4*)att + (size_t)tok * 24;

        float ar[24], ai[24];
        #pragma unroll
        for (int h = 0; h < H; ++h) {
            float4 t0 = at4[h*6+0], t1 = at4[h*6+1], t2 = at4[h*6+2];
            ar[h*6+0]=t0.x; ar[h*6+1]=t0.y; ar[h*6+2]=t0.z; ar[h*6+3]=t0.w;
            ar[h*6+4]=t1.x; ar[h*6+5]=t1.y;
            ai[h*6+0]=t1.z; ai[h*6+1]=t1.w;
            ai[h*6+2]=t2.x; ai[h*6+3]=t2.y; ai[h*6+4]=t2.z; ai[h*6+5]=t2.w;
        }
        float4 accr = make_float4(0.f,0.f,0.f,0.f);
        float4 acci = make_float4(0.f,0.f,0.f,0.f);
        #pragma unroll
        for (int i = 0; i < 24; ++i) {
            float4 wr = *(const float4*)(Wout_ang_r + i * 16 + c4);
            float4 wi = *(const float4*)(Wout_ang_i + i * 16 + c4);
            float r = ar[i], im = ai[i];
            accr.x += r*wr.x - im*wi.x;  accr.y += r*wr.y - im*wi.y;
            accr.z += r*wr.z - im*wi.z;  accr.w += r*wr.w - im*wi.w;
            acci.x += r*wi.x + im*wr.x;  acci.y += r*wi.y + im*wr.y;
            acci.z += r*wi.z + im*wr.z;  acci.w += r*wi.w + im*wr.w;
        }
        *(float4*)(out + (size_t)tok * 16 + c4)           = accr;
        *(float4*)(out + ANG_OUT + (size_t)tok * 16 + c4) = acci;
    }
}

// -------------------- Launch --------------------
extern "C" void kernel_launch(void* const* d_in, const int* in_sizes, int n_in,
                              void* d_out, int out_size, void* d_ws, size_t ws_size,
                              hipStream_t stream)
{
    const float* x_ang      = (const float*)d_in[0];
    const float* x_amp      = (const float*)d_in[1];
    const float* Wq_amp     = (const float*)d_in[2];
    const float* Wk_amp     = (const float*)d_in[3];
    const float* Wv_amp     = (const float*)d_in[4];
    const float* Wq_ang_r   = (const float*)d_in[5];
    const float* Wq_ang_i   = (const float*)d_in[6];
    const float* Wk_ang_r   = (const float*)d_in[7];
    const float* Wk_ang_i   = (const float*)d_in[8];
    const float* Wv_ang_r   = (const float*)d_in[9];
    const float* Wv_ang_i   = (const float*)d_in[10];
    const float* Wout_amp   = (const float*)d_in[11];
    const float* bout_amp   = (const float*)d_in[12];
    const float* Wout_ang_r = (const float*)d_in[13];
    const float* Wout_ang_i = (const float*)d_in[14];

    float* out = (float*)d_out;
    float* att = (float*)d_ws;   // NTOK * 96 floats = 6.29 MB, token-major

    fused_qkv_attn5_kernel<<<B * H * NT, 256, 0, stream>>>(
        x_ang, x_amp, Wq_amp, Wk_amp, Wv_amp,
        Wq_ang_r, Wq_ang_i, Wk_ang_r, Wk_ang_i, Wv_ang_r, Wv_ang_i,
        att);

    proj4_kernel<<<PJ_AMP_BLOCKS + PJ_ANG_BLOCKS, 256, 0, stream>>>(
        att, Wout_amp, bout_amp, Wout_ang_r, Wout_ang_i, out);
}

// Round 11
// 140.542 us; speedup vs baseline: 2.1188x; 1.0860x over previous
//
#include <hip/hip_runtime.h>
#include <hip/hip_fp16.h>

// Problem constants (from reference)
constexpr int B = 8;
constexpr int L = 2048;
constexpr int ANG = 16;
constexpr int AMP = 48;
constexpr int H = 4;
constexpr int AQK = 12, GQK = 6;
constexpr int LOOKBACK = 100;
constexpr int NTOK = B * L;            // 16384

typedef __fp16 f16x2 __attribute__((ext_vector_type(2)));

__device__ inline f16x2 pkrtz(float a, float b) {
    return __builtin_amdgcn_cvt_pkrtz(a, b);
}
__device__ inline float2 up2(f16x2 v) { return make_float2((float)v[0], (float)v[1]); }

__device__ inline float fdot2f(f16x2 a, f16x2 b, float c) {
#if __has_builtin(__builtin_amdgcn_fdot2)
    return __builtin_amdgcn_fdot2(a, b, c, false);
#else
    return c + (float)a[0] * (float)b[0] + (float)a[1] * (float)b[1];
#endif
}

union F4H { float4 v; f16x2 h[4]; };

// ---------------- Kernel 1: QKV projections (token-parallel, NO halo duplication) ----------------
// Block = 64 tokens x 4 heads (256 thr). tid = h*64+tok_local -> each wave has a
// single h => weight addresses wave-uniform (s_load). x staged fp32 (stride 81,
// odd -> conflict-free). Each (token,head) projected exactly ONCE (vs 2.55x in
// the fused R10 kernel). Q/K/V stored fp16: [bh][tok][24] (48B rows, 3 float4).
constexpr int QT = 64;
constexpr int QKV_BLOCKS = NTOK / QT;      // 256

__global__ __launch_bounds__(256) void qkv6_kernel(
    const float* __restrict__ x_ang, const float* __restrict__ x_amp,
    const float* __restrict__ Wq_amp, const float* __restrict__ Wk_amp,
    const float* __restrict__ Wv_amp,
    const float* __restrict__ Wq_ang_r, const float* __restrict__ Wq_ang_i,
    const float* __restrict__ Wk_ang_r, const float* __restrict__ Wk_ang_i,
    const float* __restrict__ Wv_ang_r, const float* __restrict__ Wv_ang_i,
    __fp16* __restrict__ qg, __fp16* __restrict__ kg, __fp16* __restrict__ vg)
{
    __shared__ float xs[QT][81];   // cols 0..47 amp, 48..63 ang_re, 64..79 ang_im
    const int tid  = threadIdx.x;
    const int tok0 = blockIdx.x * QT;

    {
        const float4* xm4 = (const float4*)(x_amp + (size_t)tok0 * AMP);
        for (int c = tid; c < QT * 12; c += 256) {
            int r = c / 12, i = c % 12;
            float4 t = xm4[c];
            float* p = &xs[r][4 * i];
            p[0]=t.x; p[1]=t.y; p[2]=t.z; p[3]=t.w;
        }
        const float4* xg4 = (const float4*)(x_ang + (size_t)tok0 * (2 * ANG));
        for (int c = tid; c < QT * 8; c += 256) {
            int r = c / 8, i = c % 8;
            float4 t = xg4[c];
            float* p = &xs[r][48 + 4 * i];
            p[0]=t.x; p[1]=t.y; p[2]=t.z; p[3]=t.w;
        }
    }
    __syncthreads();

    const int h  = tid >> 6;       // wave-uniform
    const int tl = tid & 63;

    // d-order: [re0..5, im0..5, amp0..11]
    float qd[24], kd[24], vd[24];
    #pragma unroll
    for (int c = 0; c < 24; ++c) { qd[c]=0.f; kd[c]=0.f; vd[c]=0.f; }

    #pragma unroll
    for (int i = 0; i < AMP; ++i) {
        float x = xs[tl][i];
        const float* wq = Wq_amp + i * 48 + h * AQK;
        const float* wk = Wk_amp + i * 48 + h * AQK;
        const float* wv = Wv_amp + i * 48 + h * AQK;
        #pragma unroll
        for (int c = 0; c < 12; ++c) {
            qd[12+c] += x * wq[c];
            kd[12+c] += x * wk[c];
            vd[12+c] += x * wv[c];
        }
    }
    #pragma unroll
    for (int i = 0; i < ANG; ++i) {
        float xr = xs[tl][48 + i], xi = xs[tl][64 + i];
        const float* wqr = Wq_ang_r + i * 24 + h * GQK;
        const float* wqi = Wq_ang_i + i * 24 + h * GQK;
        const float* wkr = Wk_ang_r + i * 24 + h * GQK;
        const float* wki = Wk_ang_i + i * 24 + h * GQK;
        const float* wvr = Wv_ang_r + i * 24 + h * GQK;
        const float* wvi = Wv_ang_i + i * 24 + h * GQK;
        #pragma unroll
        for (int c = 0; c < 6; ++c) {
            qd[c]   += xr * wqr[c] - xi * wqi[c];
            qd[6+c] += xr * wqi[c] + xi * wqr[c];
            kd[c]   += xr * wkr[c] - xi * wki[c];
            kd[6+c] += xr * wki[c] + xi * wkr[c];
            vd[c]   += xr * wvr[c] - xi * wvi[c];
            vd[6+c] += xr * wvi[c] + xi * wvr[c];
        }
    }

    const int bb = tok0 / L;               // whole block in one b (L % QT == 0)
    const int ll = (tok0 % L) + tl;
    const size_t row = ((size_t)(bb * H + h) * L + ll) * 3;   // float4 units
    #pragma unroll
    for (int sl = 0; sl < 3; ++sl) {
        F4H fq, fk, fv;
        #pragma unroll
        for (int j = 0; j < 4; ++j) {
            fq.h[j] = pkrtz(qd[8*sl + 2*j], qd[8*sl + 2*j + 1]);
            fk.h[j] = pkrtz(kd[8*sl + 2*j], kd[8*sl + 2*j + 1]);
            fv.h[j] = pkrtz(vd[8*sl + 2*j], vd[8*sl + 2*j + 1]);
        }
        ((float4*)qg)[row + sl] = fq.v;
        ((float4*)kg)[row + sl] = fk.v;
        ((float4*)vg)[row + sl] = fv.v;
    }
}

// ---------------- Kernel 2: banded attention (fp16 K/V/Q, fdot2 QK) ----------------
// Block = (b,h,64-query tile), 256 thr = 4 waves. Stage K/V fp16 rows (48B,
// coalesced; natural (12r)%32 bank spread = free 2-way). Phase C: wave = 16
// queries x 4 split-K groups, two-pass softmax, QK via v_dot2_f32_f16,
// PV via p*(float)v (v_fma_mix), shfl_xor merge. No projection work here.
constexpr int TQ     = 64;
constexpr int GROUPS = 4;
constexpr int CHUNK  = 25;                 // ceil(LOOKBACK/GROUPS)
constexpr int MAXK   = TQ + LOOKBACK - 1;  // 163
constexpr int NT     = L / TQ;             // 32

__global__ __launch_bounds__(256, 2) void attn7_kernel(
    const __fp16* __restrict__ qg, const __fp16* __restrict__ kg,
    const __fp16* __restrict__ vg, float* __restrict__ att)
{
    __shared__ float4 Ks[MAXK][3];
    __shared__ float4 Vs[MAXK][3];

    const int tid = threadIdx.x;
    const int bh  = blockIdx.x / NT;
    const int qt  = blockIdx.x % NT;
    const int b   = bh / H, h = bh % H;
    const int q0  = qt * TQ;
    int kmin = q0 - (LOOKBACK - 1); if (kmin < 0) kmin = 0;
    const int nrows = q0 + TQ - kmin;      // <= 163

    // stage K/V (coalesced float4)
    {
        const float4* kb = (const float4*)kg + ((size_t)bh * L + kmin) * 3;
        const float4* vb = (const float4*)vg + ((size_t)bh * L + kmin) * 3;
        int ntot = nrows * 3;
        for (int c = tid; c < ntot; c += 256) {
            Ks[c / 3][c % 3] = kb[c];
            Vs[c / 3][c % 3] = vb[c];
        }
        float4 z = make_float4(0.f, 0.f, 0.f, 0.f);
        for (int c = ntot + tid; c < MAXK * 3; c += 256) {
            Ks[c / 3][c % 3] = z;      // masked lanes still read rows >= nrows
            Vs[c / 3][c % 3] = z;      // in early tiles -> keep them finite
        }
    }
    __syncthreads();

    const int lane = tid & 63;
    const int w    = tid >> 6;             // wave -> queries w*16..w*16+15
    const int q16  = lane & 15;
    const int g    = lane >> 4;            // split-K group 0..3
    const int ql   = w * 16 + q16;
    const int qi   = q0 + ql;

    // load this query's fp16 row (4 dup lanes share -> L1 broadcast)
    f16x2 qh[12];
    {
        const float4* qrow = (const float4*)qg + ((size_t)bh * L + qi) * 3;
        F4H a0, a1, a2;
        a0.v = qrow[0]; a1.v = qrow[1]; a2.v = qrow[2];
        #pragma unroll
        for (int j = 0; j < 4; ++j) {
            qh[j] = a0.h[j]; qh[4 + j] = a1.h[j]; qh[8 + j] = a2.h[j];
        }
    }

    const float scale = 0.2041241452319315f; // 1/sqrt(24)
    int j0 = qi - (LOOKBACK - 1); if (j0 < 0) j0 = 0;
    const int jstart = j0 + g;

    float sc[CHUNK];
    #pragma unroll
    for (int t = 0; t < CHUNK; ++t) {
        int j = jstart + t * GROUPS;
        int r = j - kmin;
        F4H k0, k1, k2;
        k0.v = Ks[r][0]; k1.v = Ks[r][1]; k2.v = Ks[r][2];
        float d = 0.f;
        #pragma unroll
        for (int jj = 0; jj < 4; ++jj) d = fdot2f(qh[jj],     k0.h[jj], d);
        #pragma unroll
        for (int jj = 0; jj < 4; ++jj) d = fdot2f(qh[4 + jj], k1.h[jj], d);
        #pragma unroll
        for (int jj = 0; jj < 4; ++jj) d = fdot2f(qh[8 + jj], k2.h[jj], d);
        sc[t] = (j <= qi) ? d * scale : -3.0e38f;
    }
    float m = sc[0];
    #pragma unroll
    for (int t = 1; t < CHUNK; ++t) m = fmaxf(m, sc[t]);
    float ssum = 0.f;
    #pragma unroll
    for (int t = 0; t < CHUNK; ++t) {
        float p = __expf(sc[t] - m);
        p = (sc[t] > -1.0e37f) ? p : 0.f;
        sc[t] = p;
        ssum += p;
    }
    float o[24];
    #pragma unroll
    for (int e = 0; e < 24; ++e) o[e] = 0.f;
    #pragma unroll
    for (int t = 0; t < CHUNK; ++t) {
        float p = sc[t];
        int j = jstart + t * GROUPS;
        int r = j - kmin;
        #pragma unroll
        for (int sl = 0; sl < 3; ++sl) {
            F4H vv; vv.v = Vs[r][sl];
            #pragma unroll
            for (int jj = 0; jj < 4; ++jj) {
                float2 a = up2(vv.h[jj]);          // folds to v_fma_mix
                o[8*sl + 2*jj]     += p * a.x;
                o[8*sl + 2*jj + 1] += p * a.y;
            }
        }
    }

    // merge across the 4 groups (lanes xor 16, xor 32) — exact algebra
    #pragma unroll
    for (int d = 16; d <= 32; d <<= 1) {
        float m2 = __shfl_xor(m, d);
        float s2 = __shfl_xor(ssum, d);
        float mm = fmaxf(m, m2);
        float c1 = __expf(m - mm);
        float c2 = __expf(m2 - mm);
        ssum = ssum * c1 + s2 * c2;
        #pragma unroll
        for (int e = 0; e < 24; ++e)
            o[e] = o[e] * c1 + __shfl_xor(o[e], d) * c2;
        m = mm;
    }
    float inv = 1.f / ssum;

    // write att token-major [tok][h*24+d]; 4 duplicate lanes split the 6 slots
    {
        float4* dst = (float4*)att + (size_t)(b * L + qi) * 24 + h * 6;
        if (g == 0) {
            dst[0] = make_float4(o[0]*inv,  o[1]*inv,  o[2]*inv,  o[3]*inv);
            dst[4] = make_float4(o[16]*inv, o[17]*inv, o[18]*inv, o[19]*inv);
        } else if (g == 1) {
            dst[1] = make_float4(o[4]*inv,  o[5]*inv,  o[6]*inv,  o[7]*inv);
            dst[5] = make_float4(o[20]*inv, o[21]*inv, o[22]*inv, o[23]*inv);
        } else if (g == 2) {
            dst[2] = make_float4(o[8]*inv,  o[9]*inv,  o[10]*inv, o[11]*inv);
        } else {
            dst[3] = make_float4(o[12]*inv, o[13]*inv, o[14]*inv, o[15]*inv);
        }
    }
}

// ---------------- Kernel 3: output projections (4 outputs per thread) ----------------
constexpr int PJ_AMP_BLOCKS = (NTOK * 12) / 256;   // 768
constexpr int PJ_ANG_BLOCKS = (NTOK * 4) / 256;    // 256

__global__ __launch_bounds__(256) void proj4_kernel(
    const float* __restrict__ att,
    const float* __restrict__ Wout_amp, const float* __restrict__ bout_amp,
    const float* __restrict__ Wout_ang_r, const float* __restrict__ Wout_ang_i,
    float* __restrict__ out)
{
    constexpr size_t ANG_OUT = (size_t)NTOK * ANG; // 262144
    int bid = blockIdx.x;

    if (bid < PJ_AMP_BLOCKS) {
        int gidx = bid * 256 + threadIdx.x;
        int c4   = (gidx % 12) * 4;     // 0..44
        int tok  = gidx / 12;
        const float4* at4 = (const float4*)att + (size_t)tok * 24;

        float a[48];
        #pragma unroll
        for (int h = 0; h < H; ++h) {
            #pragma unroll
            for (int i = 0; i < 3; ++i) {
                float4 t = at4[h * 6 + 3 + i];
                a[h*12 + 4*i+0]=t.x; a[h*12 + 4*i+1]=t.y;
                a[h*12 + 4*i+2]=t.z; a[h*12 + 4*i+3]=t.w;
            }
        }
        float4 acc = *(const float4*)(bout_amp + c4);
        #pragma unroll
        for (int i = 0; i < 48; ++i) {
            float4 w = *(const float4*)(Wout_amp + i * 48 + c4);
            acc.x += a[i]*w.x; acc.y += a[i]*w.y; acc.z += a[i]*w.z; acc.w += a[i]*w.w;
        }
        *(float4*)(out + 2*ANG_OUT + (size_t)tok * 48 + c4) = acc;
    } else {
        int gidx = (bid - PJ_AMP_BLOCKS) * 256 + threadIdx.x;
        int c4   = (gidx % 4) * 4;      // 0,4,8,12
        int tok  = gidx / 4;
        const float4* at4 = (const float4*)att + (size_t)tok * 24;

        float ar[24], ai[24];
        #pragma unroll
        for (int h = 0; h < H; ++h) {
            float4 t0 = at4[h*6+0], t1 = at4[h*6+1], t2 = at4[h*6+2];
            ar[h*6+0]=t0.x; ar[h*6+1]=t0.y; ar[h*6+2]=t0.z; ar[h*6+3]=t0.w;
            ar[h*6+4]=t1.x; ar[h*6+5]=t1.y;
            ai[h*6+0]=t1.z; ai[h*6+1]=t1.w;
            ai[h*6+2]=t2.x; ai[h*6+3]=t2.y; ai[h*6+4]=t2.z; ai[h*6+5]=t2.w;
        }
        float4 accr = make_float4(0.f,0.f,0.f,0.f);
        float4 acci = make_float4(0.f,0.f,0.f,0.f);
        #pragma unroll
        for (int i = 0; i < 24; ++i) {
            float4 wr = *(const float4*)(Wout_ang_r + i * 16 + c4);
            float4 wi = *(const float4*)(Wout_ang_i + i * 16 + c4);
            float r = ar[i], im = ai[i];
            accr.x += r*wr.x - im*wi.x;  accr.y += r*wr.y - im*wi.y;
            accr.z += r*wr.z - im*wi.z;  accr.w += r*wr.w - im*wi.w;
            acci.x += r*wi.x + im*wr.x;  acci.y += r*wi.y + im*wr.y;
            acci.z += r*wi.z + im*wr.z;  acci.w += r*wi.w + im*wr.w;
        }
        *(float4*)(out + (size_t)tok * 16 + c4)           = accr;
        *(float4*)(out + ANG_OUT + (size_t)tok * 16 + c4) = acci;
    }
}

// -------------------- Launch --------------------
extern "C" void kernel_launch(void* const* d_in, const int* in_sizes, int n_in,
                              void* d_out, int out_size, void* d_ws, size_t ws_size,
                              hipStream_t stream)
{
    const float* x_ang      = (const float*)d_in[0];
    const float* x_amp      = (const float*)d_in[1];
    const float* Wq_amp     = (const float*)d_in[2];
    const float* Wk_amp     = (const float*)d_in[3];
    const float* Wv_amp     = (const float*)d_in[4];
    const float* Wq_ang_r   = (const float*)d_in[5];
    const float* Wq_ang_i   = (const float*)d_in[6];
    const float* Wk_ang_r   = (const float*)d_in[7];
    const float* Wk_ang_i   = (const float*)d_in[8];
    const float* Wv_ang_r   = (const float*)d_in[9];
    const float* Wv_ang_i   = (const float*)d_in[10];
    const float* Wout_amp   = (const float*)d_in[11];
    const float* bout_amp   = (const float*)d_in[12];
    const float* Wout_ang_r = (const float*)d_in[13];
    const float* Wout_ang_i = (const float*)d_in[14];

    float* out = (float*)d_out;

    const size_t NQKV = (size_t)NTOK * H * 24;       // 1,572,864 halves each
    __fp16* qg = (__fp16*)d_ws;
    __fp16* kg = qg + NQKV;
    __fp16* vg = kg + NQKV;
    float*  att = (float*)(vg + NQKV);               // 6.29 MB, 16B-aligned

    qkv6_kernel<<<QKV_BLOCKS, 256, 0, stream>>>(
        x_ang, x_amp, Wq_amp, Wk_amp, Wv_amp,
        Wq_ang_r, Wq_ang_i, Wk_ang_r, Wk_ang_i, Wv_ang_r, Wv_ang_i,
        qg, kg, vg);

    attn7_kernel<<<B * H * NT, 256, 0, stream>>>(qg, kg, vg, att);

    proj4_kernel<<<PJ_AMP_BLOCKS + PJ_ANG_BLOCKS, 256, 0, stream>>>(
        att, Wout_amp, bout_amp, Wout_ang_r, Wout_ang_i, out);
}

// Round 12
// 137.461 us; speedup vs baseline: 2.1663x; 1.0224x over previous
//
#include <hip/hip_runtime.h>
#include <hip/hip_fp16.h>

// Problem constants (from reference)
constexpr int B = 8;
constexpr int L = 2048;
constexpr int ANG = 16;
constexpr int AMP = 48;
constexpr int H = 4;
constexpr int AQK = 12, GQK = 6;
constexpr int LOOKBACK = 100;
constexpr int NTOK = B * L;            // 16384

typedef __fp16 f16x2 __attribute__((ext_vector_type(2)));

__device__ inline f16x2 pkrtz(float a, float b) {
    return __builtin_amdgcn_cvt_pkrtz(a, b);
}
__device__ inline float2 up2(f16x2 v) { return make_float2((float)v[0], (float)v[1]); }

__device__ inline float fdot2f(f16x2 a, f16x2 b, float c) {
#if __has_builtin(__builtin_amdgcn_fdot2)
    return __builtin_amdgcn_fdot2(a, b, c, false);
#else
    return c + (float)a[0] * (float)b[0] + (float)a[1] * (float)b[1];
#endif
}

union F4H { float4 v; f16x2 h[4]; };

// ---------------- Kernel 1: QKV projections (token-parallel, R11-proven) ----------------
constexpr int QT = 64;
constexpr int QKV_BLOCKS = NTOK / QT;      // 256

__global__ __launch_bounds__(256) void qkv6_kernel(
    const float* __restrict__ x_ang, const float* __restrict__ x_amp,
    const float* __restrict__ Wq_amp, const float* __restrict__ Wk_amp,
    const float* __restrict__ Wv_amp,
    const float* __restrict__ Wq_ang_r, const float* __restrict__ Wq_ang_i,
    const float* __restrict__ Wk_ang_r, const float* __restrict__ Wk_ang_i,
    const float* __restrict__ Wv_ang_r, const float* __restrict__ Wv_ang_i,
    __fp16* __restrict__ qg, __fp16* __restrict__ kg, __fp16* __restrict__ vg)
{
    __shared__ float xs[QT][81];   // cols 0..47 amp, 48..63 ang_re, 64..79 ang_im
    const int tid  = threadIdx.x;
    const int tok0 = blockIdx.x * QT;

    {
        const float4* xm4 = (const float4*)(x_amp + (size_t)tok0 * AMP);
        for (int c = tid; c < QT * 12; c += 256) {
            int r = c / 12, i = c % 12;
            float4 t = xm4[c];
            float* p = &xs[r][4 * i];
            p[0]=t.x; p[1]=t.y; p[2]=t.z; p[3]=t.w;
        }
        const float4* xg4 = (const float4*)(x_ang + (size_t)tok0 * (2 * ANG));
        for (int c = tid; c < QT * 8; c += 256) {
            int r = c / 8, i = c % 8;
            float4 t = xg4[c];
            float* p = &xs[r][48 + 4 * i];
            p[0]=t.x; p[1]=t.y; p[2]=t.z; p[3]=t.w;
        }
    }
    __syncthreads();

    const int h  = tid >> 6;       // wave-uniform
    const int tl = tid & 63;

    // d-order: [re0..5, im0..5, amp0..11]
    float qd[24], kd[24], vd[24];
    #pragma unroll
    for (int c = 0; c < 24; ++c) { qd[c]=0.f; kd[c]=0.f; vd[c]=0.f; }

    #pragma unroll
    for (int i = 0; i < AMP; ++i) {
        float x = xs[tl][i];
        const float* wq = Wq_amp + i * 48 + h * AQK;
        const float* wk = Wk_amp + i * 48 + h * AQK;
        const float* wv = Wv_amp + i * 48 + h * AQK;
        #pragma unroll
        for (int c = 0; c < 12; ++c) {
            qd[12+c] += x * wq[c];
            kd[12+c] += x * wk[c];
            vd[12+c] += x * wv[c];
        }
    }
    #pragma unroll
    for (int i = 0; i < ANG; ++i) {
        float xr = xs[tl][48 + i], xi = xs[tl][64 + i];
        const float* wqr = Wq_ang_r + i * 24 + h * GQK;
        const float* wqi = Wq_ang_i + i * 24 + h * GQK;
        const float* wkr = Wk_ang_r + i * 24 + h * GQK;
        const float* wki = Wk_ang_i + i * 24 + h * GQK;
        const float* wvr = Wv_ang_r + i * 24 + h * GQK;
        const float* wvi = Wv_ang_i + i * 24 + h * GQK;
        #pragma unroll
        for (int c = 0; c < 6; ++c) {
            qd[c]   += xr * wqr[c] - xi * wqi[c];
            qd[6+c] += xr * wqi[c] + xi * wqr[c];
            kd[c]   += xr * wkr[c] - xi * wki[c];
            kd[6+c] += xr * wki[c] + xi * wkr[c];
            vd[c]   += xr * wvr[c] - xi * wvi[c];
            vd[6+c] += xr * wvi[c] + xi * wvr[c];
        }
    }

    const int bb = tok0 / L;               // whole block in one b (L % QT == 0)
    const int ll = (tok0 % L) + tl;
    const size_t row = ((size_t)(bb * H + h) * L + ll) * 3;   // float4 units
    #pragma unroll
    for (int sl = 0; sl < 3; ++sl) {
        F4H fq, fk, fv;
        #pragma unroll
        for (int j = 0; j < 4; ++j) {
            fq.h[j] = pkrtz(qd[8*sl + 2*j], qd[8*sl + 2*j + 1]);
            fk.h[j] = pkrtz(kd[8*sl + 2*j], kd[8*sl + 2*j + 1]);
            fv.h[j] = pkrtz(vd[8*sl + 2*j], vd[8*sl + 2*j + 1]);
        }
        ((float4*)qg)[row + sl] = fq.v;
        ((float4*)kg)[row + sl] = fk.v;
        ((float4*)vg)[row + sl] = fv.v;
    }
}

// ---------------- Kernel 2: fused banded attention + output projection ----------------
// Block = (b, 32-query tile), ALL 4 heads. 512 thr = 8 waves = 4 heads x 2
// query-halves. Per-wave attention = attn7 core (16 q x 4 split-K groups,
// two-pass softmax, fdot2 QK, fma_mix PV, shfl_xor merge). Merged outputs ->
// att_s[32][100] LDS (stride 100: 4-bank row spread, float4-aligned), then the
// block computes all 80 outputs per token (thread = (tok, s): ang_r[s],
// ang_i[s], amp[s], amp[s+16], amp[s+32] - divergence-free).
// All 131 staged rows are in-bounds real data (kmin+130 <= L-1 always);
// out-of-band keys masked via sc -> p=0, so no zero-fill needed.
constexpr int TQ2    = 32;
constexpr int GROUPS = 4;
constexpr int CHUNK  = 25;                  // ceil(LOOKBACK/GROUPS)
constexpr int MAXK2  = TQ2 + LOOKBACK - 1;  // 131
constexpr int NT2    = L / TQ2;             // 64

__global__ __launch_bounds__(512, 2) void attn_proj_kernel(
    const __fp16* __restrict__ qg, const __fp16* __restrict__ kg,
    const __fp16* __restrict__ vg,
    const float* __restrict__ Wout_amp, const float* __restrict__ bout_amp,
    const float* __restrict__ Wout_ang_r, const float* __restrict__ Wout_ang_i,
    float* __restrict__ out)
{
    __shared__ float4 Ks[H][MAXK2][3];
    __shared__ float4 Vs[H][MAXK2][3];
    __shared__ float  att_s[TQ2][100];      // [ql][h*24 + d]

    const int tid = threadIdx.x;
    const int b   = blockIdx.x >> 6;        // NT2 = 64
    const int qt  = blockIdx.x & 63;
    const int q0  = qt * TQ2;
    int kmin = q0 - (LOOKBACK - 1); if (kmin < 0) kmin = 0;

    // ---- stage K/V for all 4 heads (full 131 rows, always in-bounds) ----
    {
        const float4* kb = (const float4*)kg;
        const float4* vb = (const float4*)vg;
        for (int c = tid; c < H * MAXK2 * 3; c += 512) {
            int hh  = c / (MAXK2 * 3);
            int rem = c % (MAXK2 * 3);
            int r   = rem / 3, sl = rem % 3;
            size_t gi = ((size_t)(b * H + hh) * L + kmin + r) * 3 + sl;
            Ks[hh][r][sl] = kb[gi];
            Vs[hh][r][sl] = vb[gi];
        }
    }
    __syncthreads();

    // ---- attention (per-wave: head h, query-half qh) ----
    const int ww   = tid >> 6;              // wave 0..7
    const int lane = tid & 63;
    const int h    = ww & 3;                // wave-uniform head
    const int qh   = ww >> 2;               // 0/1
    const int q16  = lane & 15;
    const int g    = lane >> 4;             // split-K group 0..3
    const int ql   = qh * 16 + q16;
    const int qi   = q0 + ql;

    f16x2 qhv[12];
    {
        const float4* qrow = (const float4*)qg + ((size_t)(b * H + h) * L + qi) * 3;
        F4H a0, a1, a2;
        a0.v = qrow[0]; a1.v = qrow[1]; a2.v = qrow[2];
        #pragma unroll
        for (int j = 0; j < 4; ++j) {
            qhv[j] = a0.h[j]; qhv[4 + j] = a1.h[j]; qhv[8 + j] = a2.h[j];
        }
    }

    const float scale = 0.2041241452319315f; // 1/sqrt(24)
    int j0 = qi - (LOOKBACK - 1); if (j0 < 0) j0 = 0;
    const int jstart = j0 + g;

    float sc[CHUNK];
    #pragma unroll
    for (int t = 0; t < CHUNK; ++t) {
        int j = jstart + t * GROUPS;
        int r = j - kmin;
        F4H k0, k1, k2;
        k0.v = Ks[h][r][0]; k1.v = Ks[h][r][1]; k2.v = Ks[h][r][2];
        float d = 0.f;
        #pragma unroll
        for (int jj = 0; jj < 4; ++jj) d = fdot2f(qhv[jj],     k0.h[jj], d);
        #pragma unroll
        for (int jj = 0; jj < 4; ++jj) d = fdot2f(qhv[4 + jj], k1.h[jj], d);
        #pragma unroll
        for (int jj = 0; jj < 4; ++jj) d = fdot2f(qhv[8 + jj], k2.h[jj], d);
        sc[t] = (j <= qi) ? d * scale : -3.0e38f;
    }
    float m = sc[0];
    #pragma unroll
    for (int t = 1; t < CHUNK; ++t) m = fmaxf(m, sc[t]);
    float ssum = 0.f;
    #pragma unroll
    for (int t = 0; t < CHUNK; ++t) {
        float p = __expf(sc[t] - m);
        p = (sc[t] > -1.0e37f) ? p : 0.f;
        sc[t] = p;
        ssum += p;
    }
    float o[24];
    #pragma unroll
    for (int e = 0; e < 24; ++e) o[e] = 0.f;
    #pragma unroll
    for (int t = 0; t < CHUNK; ++t) {
        float p = sc[t];
        int j = jstart + t * GROUPS;
        int r = j - kmin;
        #pragma unroll
        for (int sl = 0; sl < 3; ++sl) {
            F4H vv; vv.v = Vs[h][r][sl];
            #pragma unroll
            for (int jj = 0; jj < 4; ++jj) {
                float2 a = up2(vv.h[jj]);          // folds to v_fma_mix
                o[8*sl + 2*jj]     += p * a.x;
                o[8*sl + 2*jj + 1] += p * a.y;
            }
        }
    }

    // merge across the 4 groups (lanes xor 16, xor 32) — exact algebra
    #pragma unroll
    for (int d = 16; d <= 32; d <<= 1) {
        float m2 = __shfl_xor(m, d);
        float s2 = __shfl_xor(ssum, d);
        float mm = fmaxf(m, m2);
        float c1 = __expf(m - mm);
        float c2 = __expf(m2 - mm);
        ssum = ssum * c1 + s2 * c2;
        #pragma unroll
        for (int e = 0; e < 24; ++e)
            o[e] = o[e] * c1 + __shfl_xor(o[e], d) * c2;
        m = mm;
    }
    float inv = 1.f / ssum;

    // write att_s[ql][h*24 + d] = o[d]*inv ; duplicate lanes split 6 slots
    {
        float* arow = &att_s[ql][h * 24];
        if (g == 0) {
            *(float4*)(arow +  0) = make_float4(o[0]*inv,  o[1]*inv,  o[2]*inv,  o[3]*inv);
            *(float4*)(arow + 16) = make_float4(o[16]*inv, o[17]*inv, o[18]*inv, o[19]*inv);
        } else if (g == 1) {
            *(float4*)(arow +  4) = make_float4(o[4]*inv,  o[5]*inv,  o[6]*inv,  o[7]*inv);
            *(float4*)(arow + 20) = make_float4(o[20]*inv, o[21]*inv, o[22]*inv, o[23]*inv);
        } else if (g == 2) {
            *(float4*)(arow +  8) = make_float4(o[8]*inv,  o[9]*inv,  o[10]*inv, o[11]*inv);
        } else {
            *(float4*)(arow + 12) = make_float4(o[12]*inv, o[13]*inv, o[14]*inv, o[15]*inv);
        }
    }
    __syncthreads();

    // ---- output projection: thread = (tok, s); 5 outputs ----
    {
        constexpr size_t ANG_OUT = (size_t)NTOK * ANG; // 262144
        const int tok = tid >> 4;          // 0..31
        const int s   = tid & 15;          // 0..15
        const float* arow = att_s[tok];
        const size_t tokg = (size_t)b * L + q0 + tok;

        float accr = 0.f, acci = 0.f;
        #pragma unroll
        for (int h2 = 0; h2 < H; ++h2) {
            #pragma unroll
            for (int c = 0; c < 6; ++c) {
                float ar = arow[h2*24 + c], ai = arow[h2*24 + 6 + c];
                int rw = h2 * 6 + c;
                float wr = Wout_ang_r[rw * 16 + s];
                float wi = Wout_ang_i[rw * 16 + s];
                accr += ar * wr - ai * wi;
                acci += ar * wi + ai * wr;
            }
        }
        out[tokg * 16 + s]           = accr;
        out[ANG_OUT + tokg * 16 + s] = acci;

        float a0 = bout_amp[s], a1 = bout_amp[s + 16], a2 = bout_amp[s + 32];
        #pragma unroll
        for (int h2 = 0; h2 < H; ++h2) {
            #pragma unroll
            for (int c = 0; c < 12; ++c) {
                float xa = arow[h2*24 + 12 + c];
                const float* wrow = Wout_amp + (h2 * 12 + c) * 48;
                a0 += xa * wrow[s];
                a1 += xa * wrow[s + 16];
                a2 += xa * wrow[s + 32];
            }
        }
        float* ob = out + 2 * ANG_OUT + tokg * 48;
        ob[s]      = a0;
        ob[s + 16] = a1;
        ob[s + 32] = a2;
    }
}

// -------------------- Launch --------------------
extern "C" void kernel_launch(void* const* d_in, const int* in_sizes, int n_in,
                              void* d_out, int out_size, void* d_ws, size_t ws_size,
                              hipStream_t stream)
{
    const float* x_ang      = (const float*)d_in[0];
    const float* x_amp      = (const float*)d_in[1];
    const float* Wq_amp     = (const float*)d_in[2];
    const float* Wk_amp     = (const float*)d_in[3];
    const float* Wv_amp     = (const float*)d_in[4];
    const float* Wq_ang_r   = (const float*)d_in[5];
    const float* Wq_ang_i   = (const float*)d_in[6];
    const float* Wk_ang_r   = (const float*)d_in[7];
    const float* Wk_ang_i   = (const float*)d_in[8];
    const float* Wv_ang_r   = (const float*)d_in[9];
    const float* Wv_ang_i   = (const float*)d_in[10];
    const float* Wout_amp   = (const float*)d_in[11];
    const float* bout_amp   = (const float*)d_in[12];
    const float* Wout_ang_r = (const float*)d_in[13];
    const float* Wout_ang_i = (const float*)d_in[14];

    float* out = (float*)d_out;

    const size_t NQKV = (size_t)NTOK * H * 24;       // 1,572,864 halves each
    __fp16* qg = (__fp16*)d_ws;
    __fp16* kg = qg + NQKV;
    __fp16* vg = kg + NQKV;

    qkv6_kernel<<<QKV_BLOCKS, 256, 0, stream>>>(
        x_ang, x_amp, Wq_amp, Wk_amp, Wv_amp,
        Wq_ang_r, Wq_ang_i, Wk_ang_r, Wk_ang_i, Wv_ang_r, Wv_ang_i,
        qg, kg, vg);

    attn_proj_kernel<<<B * NT2, 512, 0, stream>>>(
        qg, kg, vg, Wout_amp, bout_amp, Wout_ang_r, Wout_ang_i, out);
}